// Round 5
// baseline (220.607 us; speedup 1.0000x reference)
//
#include <hip/hip_runtime.h>

typedef __attribute__((ext_vector_type(8))) short bf16x8;
typedef __attribute__((ext_vector_type(4))) float f32x4;
typedef __attribute__((ext_vector_type(16))) float f32x16;

__device__ __forceinline__ ushort f2bf(float f) {
  union { float f; unsigned u; } v; v.f = f;
  unsigned r = v.u + 0x7fffu + ((v.u >> 16) & 1u);
  return (ushort)(r >> 16);
}

__device__ __forceinline__ float bf2f(ushort u) {
  union { float f; unsigned u; } v; v.u = (unsigned)u << 16;
  return v.f;
}

__device__ __forceinline__ unsigned cvt_pk_bf16(float lo, float hi) {
  unsigned r;
  asm("v_cvt_pk_bf16_f32 %0, %1, %2" : "=v"(r) : "v"(lo), "v"(hi));
  return r;
}

__device__ __forceinline__ void permlane32_swap(unsigned& x, unsigned& y) {
  asm("v_permlane32_swap_b32 %0, %1" : "+v"(x), "+v"(y));
}

__device__ __forceinline__ void gload_lds16(const void* g, void* l) {
  __builtin_amdgcn_global_load_lds(
      (const __attribute__((address_space(1))) void*)g,
      (__attribute__((address_space(3))) void*)l, 16, 0, 0);
}

// ---------------- conversion kernels ----------------

__global__ void cvt_f32_bf16(const float* __restrict__ s, ushort* __restrict__ d, int n) {
  int i = (blockIdx.x * blockDim.x + threadIdx.x) * 4;
  int stride = gridDim.x * blockDim.x * 4;
  for (; i < n; i += stride) {
    float4 v = *reinterpret_cast<const float4*>(s + i);
    ushort4 o;
    o.x = f2bf(v.x); o.y = f2bf(v.y); o.z = f2bf(v.z); o.w = f2bf(v.w);
    *reinterpret_cast<ushort4*>(d + i) = o;
  }
}

// src [R][C] f32 -> dst [C][R] bf16
__global__ void transpose_cvt(const float* __restrict__ src, ushort* __restrict__ dst,
                              int R, int C) {
  __shared__ float tile[32][33];
  int c0 = blockIdx.x * 32, r0 = blockIdx.y * 32;
  int tx = threadIdx.x, ty = threadIdx.y;  // 32 x 8
  #pragma unroll
  for (int i = 0; i < 32; i += 8)
    tile[ty + i][tx] = src[(size_t)(r0 + ty + i) * C + c0 + tx];
  __syncthreads();
  #pragma unroll
  for (int i = 0; i < 32; i += 8)
    dst[(size_t)(c0 + ty + i) * R + r0 + tx] = f2bf(tile[tx][ty + i]);
}

// ---------------- GEMM1: 256x256 8-phase (T2+T3+T4+T5) ----------------
// A [8192][1024] bf16, Bt [3072][1024] bf16. 8 waves (2M x 4N), per-wave 128x64.
// LDS [2 buf][256 rows][64 k] per operand, row = 128 B, swizzle byte ^= (row&7)<<4.
// Per K-tile: 4 phases (quadrants A0B0, A0B1, A1B1, A1B0); stage 1 half-tile/phase;
// single counted vmcnt(4) per K-tile at q3 validating tile T+1.

#define STAGE_HALF(dstbuf, srcp, base, t, half)                                    \
  {                                                                                \
    _Pragma("unroll")                                                              \
    for (int l_ = 0; l_ < 2; ++l_) {                                               \
      const int r_ = (half) * 128 + l_ * 64 + sr;                                  \
      gload_lds16(srcp + (size_t)((base) + r_) * 1024 + (t) * 64 + scg,            \
                  (char*)&dstbuf[(t) & 1][0] + (half) * 16384 + l_ * 8192 + tid * 16); \
    }                                                                              \
  }

#define LDA8(mh)                                                                   \
  {                                                                                \
    _Pragma("unroll")                                                              \
    for (int mi = 0; mi < 4; ++mi) {                                               \
      const int row_ = wm * 128 + (mh) * 64 + mi * 16 + lr;                        \
      const char* p_ = (const char*)&sA[cur][0] + row_ * 128;                      \
      const int sw_ = (row_ & 7) << 4;                                             \
      af[mi * 2 + 0] = *(const bf16x8*)(p_ + ((lg * 16) ^ sw_));                   \
      af[mi * 2 + 1] = *(const bf16x8*)(p_ + ((64 + lg * 16) ^ sw_));              \
    }                                                                              \
  }

#define LDB4(nh)                                                                   \
  {                                                                                \
    _Pragma("unroll")                                                              \
    for (int ni = 0; ni < 2; ++ni) {                                               \
      const int row_ = wn * 64 + (nh) * 32 + ni * 16 + lr;                         \
      const char* p_ = (const char*)&sB[cur][0] + row_ * 128;                      \
      const int sw_ = (row_ & 7) << 4;                                             \
      bf[ni * 2 + 0] = *(const bf16x8*)(p_ + ((lg * 16) ^ sw_));                   \
      bf[ni * 2 + 1] = *(const bf16x8*)(p_ + ((64 + lg * 16) ^ sw_));              \
    }                                                                              \
  }

#define MMQ(mh, nh)                                                                \
  {                                                                                \
    _Pragma("unroll")                                                              \
    for (int kk = 0; kk < 2; ++kk)                                                 \
      _Pragma("unroll")                                                            \
      for (int mi = 0; mi < 4; ++mi)                                               \
        _Pragma("unroll")                                                          \
        for (int ni = 0; ni < 2; ++ni)                                             \
          acc[mh][mi][nh][ni] = __builtin_amdgcn_mfma_f32_16x16x32_bf16(           \
              af[mi * 2 + kk], bf[ni * 2 + kk], acc[mh][mi][nh][ni], 0, 0, 0);     \
  }

#define PH_SYNC_MFMA(mh, nh)                                                       \
  __builtin_amdgcn_s_barrier();                                                    \
  asm volatile("s_waitcnt lgkmcnt(0)" ::: "memory");                               \
  __builtin_amdgcn_sched_barrier(0);                                               \
  __builtin_amdgcn_s_setprio(1);                                                   \
  MMQ(mh, nh);                                                                     \
  __builtin_amdgcn_s_setprio(0);                                                   \
  __builtin_amdgcn_s_barrier();

__global__ __launch_bounds__(512, 2) void gemm_qkv(const ushort* __restrict__ A,
                                                   const ushort* __restrict__ Bt,
                                                   const float* __restrict__ bias,
                                                   ushort* __restrict__ q,
                                                   ushort* __restrict__ k,
                                                   ushort* __restrict__ vT) {
  __shared__ __align__(16) ushort sA[2][256 * 64];
  __shared__ __align__(16) ushort sB[2][256 * 64];
  const int tid = threadIdx.x, lane = tid & 63, w = tid >> 6;
  const int wm = w >> 2, wn = w & 3;
  const int bm = blockIdx.y * 256, bn = blockIdx.x * 256;
  const int lr = lane & 15, lg = lane >> 4;
  const int sr = tid >> 3;                       // staging row within 8KB piece
  const int scg = ((tid & 7) ^ (sr & 7)) * 8;    // inverse-swizzled source chunk

  f32x4 acc[2][4][2][2] = {};
  bf16x8 af[8], bf[4];

  // prologue issue order: t0.A0, t0.B1, t0.A1, t0.B0, t1.A0, t1.B1
  STAGE_HALF(sA, A, bm, 0, 0);
  STAGE_HALF(sB, Bt, bn, 0, 1);
  STAGE_HALF(sA, A, bm, 0, 1);
  STAGE_HALF(sB, Bt, bn, 0, 0);
  STAGE_HALF(sA, A, bm, 1, 0);
  STAGE_HALF(sB, Bt, bn, 1, 1);
  asm volatile("s_waitcnt vmcnt(4)" ::: "memory");
  __builtin_amdgcn_s_barrier();

  for (int T = 0; T < 16; ++T) {
    const int cur = T & 1;
    // q0: compute (A0,B0); stage (T+1).A1
    LDA8(0); LDB4(0);
    if (T + 1 < 16) STAGE_HALF(sA, A, bm, T + 1, 1);
    PH_SYNC_MFMA(0, 0);
    // q1: compute (A0,B1); stage (T+1).B0
    LDB4(1);
    if (T + 1 < 16) STAGE_HALF(sB, Bt, bn, T + 1, 0);
    PH_SYNC_MFMA(0, 1);
    // q2: compute (A1,B1); stage (T+2).A0
    LDA8(1);
    if (T + 2 < 16) STAGE_HALF(sA, A, bm, T + 2, 0);
    PH_SYNC_MFMA(1, 1);
    // q3: compute (A1,B0); stage (T+2).B1; counted vmcnt validates tile T+1
    LDB4(0);
    if (T + 2 < 16) STAGE_HALF(sB, Bt, bn, T + 2, 1);
    if (T < 14) { asm volatile("s_waitcnt vmcnt(4)" ::: "memory"); }
    else        { asm volatile("s_waitcnt vmcnt(0)" ::: "memory"); }
    PH_SYNC_MFMA(1, 0);
  }

  // epilogue: scatter with bias. col -> (q|k|v, head, d); v transposed.
  #pragma unroll
  for (int mh = 0; mh < 2; ++mh)
    #pragma unroll
    for (int mi = 0; mi < 4; ++mi)
      #pragma unroll
      for (int nh = 0; nh < 2; ++nh)
        #pragma unroll
        for (int ni = 0; ni < 2; ++ni) {
          const int col = bn + wn * 64 + nh * 32 + ni * 16 + lr;
          const int t = col >> 10;
          const int h = (col >> 6) & 15;
          const int d = col & 63;
          const float bb = bias[col];
          #pragma unroll
          for (int rr = 0; rr < 4; ++rr) {
            const int row = bm + wm * 128 + mh * 64 + mi * 16 + lg * 4 + rr;
            const int b_ = row >> 11, n = row & 2047;
            const int bh = b_ * 16 + h;
            const ushort hv = f2bf(acc[mh][mi][nh][ni][rr] + bb);
            if (t == 0)      q[((size_t)bh * 2048 + n) * 64 + d] = hv;
            else if (t == 1) k[((size_t)bh * 2048 + n) * 64 + d] = hv;
            else             vT[((size_t)bh * 64 + d) * 2048 + n] = hv;
          }
        }
}

// ---------------- flash attention v4: 32x32 MFMA, in-register P ----------------

__global__ __launch_bounds__(512, 2) void attn_fwd(const ushort* __restrict__ q,
                                                   const ushort* __restrict__ k,
                                                   const ushort* __restrict__ vT,
                                                   ushort* __restrict__ o) {
  __shared__ __align__(16) ushort sK[2][64 * 64];
  __shared__ __align__(16) ushort sV[2][64 * 64];

  const int tid = threadIdx.x, lane = tid & 63, w = tid >> 6;
  const int id = blockIdx.x;
  const int xcd = id & 7, j = id >> 3;
  const int bh = xcd * 8 + (j & 7);
  const int qx = j >> 3;
  const int qrow0 = qx * 256 + w * 32;

  const ushort* Qb = q + (size_t)bh * 2048 * 64;
  const ushort* Kb = k + (size_t)bh * 2048 * 64;
  const ushort* Vb = vT + (size_t)bh * 64 * 2048;
  const int lq = lane & 31, hi = lane >> 5;

  const int srow = lane >> 3;
  const int ssw = ((lane & 7) ^ srow) * 8;
  const int krow = w * 8 + srow;

  gload_lds16(Kb + (size_t)krow * 64 + ssw, &sK[0][w * 512]);
  gload_lds16(Vb + (size_t)krow * 2048 + 0 + ssw, &sV[0][w * 512]);

  const float qs = 0.125f * 1.44269504f;  // 1/sqrt(64) * log2(e)
  bf16x8 qf[4];
  #pragma unroll
  for (int dk = 0; dk < 4; ++dk) {
    bf16x8 t = *(const bf16x8*)(Qb + (size_t)(qrow0 + lq) * 64 + dk * 16 + hi * 8);
    #pragma unroll
    for (int jj = 0; jj < 8; ++jj)
      t[jj] = (short)f2bf(bf2f((ushort)t[jj]) * qs);
    qf[dk] = t;
  }

  float m_run = -1e30f, l_run = 0.f;
  f32x16 oacc[2] = {};

  for (int t = 0; t < 32; ++t) {
    const int cur = t & 1;
    if (t + 1 < 32) {
      const int kv2 = (t + 1) << 6;
      gload_lds16(Kb + (size_t)(kv2 + krow) * 64 + ssw, &sK[cur ^ 1][w * 512]);
      gload_lds16(Vb + (size_t)krow * 2048 + kv2 + ssw, &sV[cur ^ 1][w * 512]);
      asm volatile("s_waitcnt vmcnt(2)" ::: "memory");
    } else {
      asm volatile("s_waitcnt vmcnt(0)" ::: "memory");
    }
    __builtin_amdgcn_s_barrier();
    __builtin_amdgcn_sched_barrier(0);

    const char* kb_ = (const char*)&sK[cur][0];
    const char* vb_ = (const char*)&sV[cur][0];

    f32x16 S[2] = {};
    __builtin_amdgcn_s_setprio(1);
    #pragma unroll
    for (int kvt = 0; kvt < 2; ++kvt) {
      const int row = kvt * 32 + lq;
      const int rsw = (row & 7) << 4;
      #pragma unroll
      for (int dk = 0; dk < 4; ++dk) {
        bf16x8 kf = *(const bf16x8*)(kb_ + row * 128 + ((dk * 32 + hi * 16) ^ rsw));
        S[kvt] = __builtin_amdgcn_mfma_f32_32x32x16_bf16(kf, qf[dk], S[kvt], 0, 0, 0);
      }
    }
    __builtin_amdgcn_s_setprio(0);

    float mx = S[0][0];
    #pragma unroll
    for (int kvt = 0; kvt < 2; ++kvt)
      #pragma unroll
      for (int r = 0; r < 16; ++r) mx = fmaxf(mx, S[kvt][r]);
    const float rm = fmaxf(mx, __shfl_xor(mx, 32, 64));

    if (!__all(rm <= m_run + 8.f)) {
      const float mnew = fmaxf(m_run, rm);
      const float corr = __builtin_amdgcn_exp2f(m_run - mnew);
      m_run = mnew;
      l_run *= corr;
      float cq[16];
      #pragma unroll
      for (int r = 0; r < 16; ++r)
        cq[r] = __shfl(corr, (r & 3) + 8 * (r >> 2) + 4 * hi, 64);
      #pragma unroll
      for (int dt = 0; dt < 2; ++dt)
        #pragma unroll
        for (int r = 0; r < 16; ++r) oacc[dt][r] *= cq[r];
    }

    float psum = 0.f;
    unsigned pk_[2][8];
    #pragma unroll
    for (int kvt = 0; kvt < 2; ++kvt) {
      float e[16];
      #pragma unroll
      for (int r = 0; r < 16; ++r) {
        e[r] = __builtin_amdgcn_exp2f(S[kvt][r] - m_run);
        psum += e[r];
      }
      #pragma unroll
      for (int g = 0; g < 4; ++g) {
        pk_[kvt][g * 2 + 0] = cvt_pk_bf16(e[4 * g + 0], e[4 * g + 1]);
        pk_[kvt][g * 2 + 1] = cvt_pk_bf16(e[4 * g + 2], e[4 * g + 3]);
      }
    }
    psum += __shfl_xor(psum, 32, 64);
    l_run += psum;

    __builtin_amdgcn_s_setprio(1);
    #pragma unroll
    for (int kvt = 0; kvt < 2; ++kvt)
      #pragma unroll
      for (int cc = 0; cc < 2; ++cc) {
        unsigned x0 = pk_[kvt][4 * cc + 0], x1 = pk_[kvt][4 * cc + 1];
        unsigned y0 = pk_[kvt][4 * cc + 2], y1 = pk_[kvt][4 * cc + 3];
        permlane32_swap(x0, y0);
        permlane32_swap(x1, y1);
        union { unsigned u[4]; bf16x8 v; } Am;
        Am.u[0] = x0; Am.u[1] = x1; Am.u[2] = y0; Am.u[3] = y1;
        const int cg = kvt * 2 + cc;
        #pragma unroll
        for (int dt = 0; dt < 2; ++dt) {
          const int row = dt * 32 + lq;
          bf16x8 vf = *(const bf16x8*)(vb_ + row * 128 + ((cg * 32 + hi * 16) ^ ((row & 7) << 4)));
          oacc[dt] = __builtin_amdgcn_mfma_f32_32x32x16_bf16(Am.v, vf, oacc[dt], 0, 0, 0);
        }
      }
    __builtin_amdgcn_s_setprio(0);
    __builtin_amdgcn_s_barrier();
  }

  const int b_ = bh >> 4, h = bh & 15;
  float lf[16];
  #pragma unroll
  for (int r = 0; r < 16; ++r)
    lf[r] = __builtin_amdgcn_rcpf(__shfl(l_run, (r & 3) + 8 * (r >> 2) + 4 * hi, 64));
  #pragma unroll
  for (int dt = 0; dt < 2; ++dt)
    #pragma unroll
    for (int r = 0; r < 16; ++r) {
      const int n = qrow0 + (r & 3) + 8 * (r >> 2) + 4 * hi;
      o[(((size_t)b_ * 2048 + n) * 16 + h) * 64 + dt * 32 + lq] = f2bf(oacc[dt][r] * lf[r]);
    }
}

// ---------------- GEMM2: out = attn @ w_out + b_out (f32 out) ----------------

__global__ void gemm_out(const ushort* __restrict__ A, const ushort* __restrict__ Bt,
                         const float* __restrict__ bias, float* __restrict__ out) {
  constexpr int K = 1024;
  __shared__ __align__(16) ushort sA[128 * 32];
  __shared__ __align__(16) ushort sB[128 * 32];
  const int tid = threadIdx.x;
  const int lane = tid & 63;
  const int w = tid >> 6;
  const int wr = w >> 1, wc = w & 1;
  const int bm = blockIdx.y * 128;
  const int bn = blockIdx.x * 128;
  f32x4 acc[4][4] = {};
  const int srow = lane >> 2;
  const int skb = (lane & 3) * 8;

  for (int kt = 0; kt < K; kt += 32) {
    #pragma unroll
    for (int i = 0; i < 2; ++i) {
      const int chunk = w * 2 + i;
      const int row = chunk * 16 + srow;
      gload_lds16(A + (size_t)(bm + row) * K + kt + skb, sA + chunk * 512);
      gload_lds16(Bt + (size_t)(bn + row) * K + kt + skb, sB + chunk * 512);
    }
    __syncthreads();
    bf16x8 af[4], bfr[4];
    #pragma unroll
    for (int mi = 0; mi < 4; ++mi)
      af[mi] = *(const bf16x8*)(sA + (wr * 64 + mi * 16 + (lane & 15)) * 32 + (lane >> 4) * 8);
    #pragma unroll
    for (int ni = 0; ni < 4; ++ni)
      bfr[ni] = *(const bf16x8*)(sB + (wc * 64 + ni * 16 + (lane & 15)) * 32 + (lane >> 4) * 8);
    #pragma unroll
    for (int mi = 0; mi < 4; ++mi)
      #pragma unroll
      for (int ni = 0; ni < 4; ++ni)
        acc[mi][ni] = __builtin_amdgcn_mfma_f32_16x16x32_bf16(af[mi], bfr[ni], acc[mi][ni], 0, 0, 0);
    __syncthreads();
  }

  #pragma unroll
  for (int mi = 0; mi < 4; ++mi)
    #pragma unroll
    for (int ni = 0; ni < 4; ++ni) {
      const int col = bn + wc * 64 + ni * 16 + (lane & 15);
      const float bb = bias[col];
      #pragma unroll
      for (int r = 0; r < 4; ++r) {
        const int row = bm + wr * 64 + mi * 16 + (lane >> 4) * 4 + r;
        out[(size_t)row * 1024 + col] = acc[mi][ni][r] + bb;
      }
    }
}

// ---------------- launch ----------------

extern "C" void kernel_launch(void* const* d_in, const int* in_sizes, int n_in,
                              void* d_out, int out_size, void* d_ws, size_t ws_size,
                              hipStream_t stream) {
  const float* x = (const float*)d_in[0];
  const float* w_qkv = (const float*)d_in[1];
  const float* b_qkv = (const float*)d_in[2];
  const float* w_out = (const float*)d_in[3];
  const float* b_out = (const float*)d_in[4];
  float* out = (float*)d_out;
  char* ws = (char*)d_ws;

  ushort* xb    = (ushort*)(ws);                 // 16 MiB
  ushort* wqkvT = (ushort*)(ws + 16777216);      // 6 MiB
  ushort* woutT = (ushort*)(ws + 23068672);      // 2 MiB
  ushort* qb    = (ushort*)(ws + 25165824);      // 16 MiB
  ushort* kb    = (ushort*)(ws + 41943040);      // 16 MiB
  ushort* vTb   = (ushort*)(ws + 58720256);      // 16 MiB
  ushort* attnb = (ushort*)(ws + 75497472);      // 16 MiB

  cvt_f32_bf16<<<2048, 256, 0, stream>>>(x, xb, 8192 * 1024);
  transpose_cvt<<<dim3(96, 32), dim3(32, 8), 0, stream>>>(w_qkv, wqkvT, 1024, 3072);
  transpose_cvt<<<dim3(32, 32), dim3(32, 8), 0, stream>>>(w_out, woutT, 1024, 1024);
  gemm_qkv<<<dim3(12, 32), 512, 0, stream>>>(xb, wqkvT, b_qkv, qb, kb, vTb);
  attn_fwd<<<512, 512, 0, stream>>>(qb, kb, vTb, attnb);
  gemm_out<<<dim3(8, 64), 256, 0, stream>>>(attnb, woutT, b_out, out);
}

// Round 6
// 217.989 us; speedup vs baseline: 1.0120x; 1.0120x over previous
//
#include <hip/hip_runtime.h>

typedef __attribute__((ext_vector_type(8))) short bf16x8;
typedef __attribute__((ext_vector_type(4))) float f32x4;
typedef __attribute__((ext_vector_type(16))) float f32x16;

__device__ __forceinline__ ushort f2bf(float f) {
  union { float f; unsigned u; } v; v.f = f;
  unsigned r = v.u + 0x7fffu + ((v.u >> 16) & 1u);
  return (ushort)(r >> 16);
}

__device__ __forceinline__ float bf2f(ushort u) {
  union { float f; unsigned u; } v; v.u = (unsigned)u << 16;
  return v.f;
}

__device__ __forceinline__ unsigned cvt_pk_bf16(float lo, float hi) {
  unsigned r;
  asm("v_cvt_pk_bf16_f32 %0, %1, %2" : "=v"(r) : "v"(lo), "v"(hi));
  return r;
}

__device__ __forceinline__ void permlane32_swap(unsigned& x, unsigned& y) {
  asm("v_permlane32_swap_b32 %0, %1" : "+v"(x), "+v"(y));
}

__device__ __forceinline__ void gload_lds16(const void* g, void* l) {
  __builtin_amdgcn_global_load_lds(
      (const __attribute__((address_space(1))) void*)g,
      (__attribute__((address_space(3))) void*)l, 16, 0, 0);
}

// ---------------- conversion kernels ----------------

__global__ void cvt_f32_bf16(const float* __restrict__ s, ushort* __restrict__ d, int n) {
  int i = (blockIdx.x * blockDim.x + threadIdx.x) * 4;
  int stride = gridDim.x * blockDim.x * 4;
  for (; i < n; i += stride) {
    float4 v = *reinterpret_cast<const float4*>(s + i);
    ushort4 o;
    o.x = f2bf(v.x); o.y = f2bf(v.y); o.z = f2bf(v.z); o.w = f2bf(v.w);
    *reinterpret_cast<ushort4*>(d + i) = o;
  }
}

// src [R][C] f32 -> dst [C][R] bf16
__global__ void transpose_cvt(const float* __restrict__ src, ushort* __restrict__ dst,
                              int R, int C) {
  __shared__ float tile[32][33];
  int c0 = blockIdx.x * 32, r0 = blockIdx.y * 32;
  int tx = threadIdx.x, ty = threadIdx.y;  // 32 x 8
  #pragma unroll
  for (int i = 0; i < 32; i += 8)
    tile[ty + i][tx] = src[(size_t)(r0 + ty + i) * C + c0 + tx];
  __syncthreads();
  #pragma unroll
  for (int i = 0; i < 32; i += 8)
    dst[(size_t)(c0 + ty + i) * R + r0 + tx] = f2bf(tile[tx][ty + i]);
}

// ---------------- GEMM core: 128x128 tile, BK=64, XOR-swizzled LDS ----------------
// m97 2-barrier structure; BK=64 halves barrier-drain count per K.
// LDS rows are 128 B (8 x 16B chunks); chunk slot = j ^ (row&7) (inverse-swizzled
// global source so global_load_lds dest stays linear, rule #21). b128 reads land
// 8 lanes per 4-bank group = optimal for wave64 b128.

#define GEMM_STAGE(kt)                                                         \
  {                                                                            \
    _Pragma("unroll")                                                          \
    for (int c_ = 0; c_ < 4; ++c_) {                                           \
      const int qq_ = c_ * 256 + tid;                                          \
      const int row_ = qq_ >> 3;                                               \
      const int so_ = ((qq_ & 7) ^ (row_ & 7)) * 8;                            \
      gload_lds16(A + (size_t)(bm + row_) * 1024 + (kt) + so_,                 \
                  (char*)sA + qq_ * 16);                                       \
      gload_lds16(Bt + (size_t)(bn + row_) * 1024 + (kt) + so_,                \
                  (char*)sB + qq_ * 16);                                       \
    }                                                                          \
  }

#define GEMM_COMPUTE()                                                         \
  {                                                                            \
    bf16x8 af[4][2], bfr[4][2];                                                \
    _Pragma("unroll")                                                          \
    for (int mi = 0; mi < 4; ++mi) {                                           \
      const int row_ = wr * 64 + mi * 16 + lr;                                 \
      const char* p_ = (const char*)sA + row_ * 128;                           \
      const int sw_ = (row_ & 7) << 4;                                         \
      af[mi][0] = *(const bf16x8*)(p_ + ((lg * 16) ^ sw_));                    \
      af[mi][1] = *(const bf16x8*)(p_ + ((64 + lg * 16) ^ sw_));               \
    }                                                                          \
    _Pragma("unroll")                                                          \
    for (int ni = 0; ni < 4; ++ni) {                                           \
      const int row_ = wc * 64 + ni * 16 + lr;                                 \
      const char* p_ = (const char*)sB + row_ * 128;                           \
      const int sw_ = (row_ & 7) << 4;                                         \
      bfr[ni][0] = *(const bf16x8*)(p_ + ((lg * 16) ^ sw_));                   \
      bfr[ni][1] = *(const bf16x8*)(p_ + ((64 + lg * 16) ^ sw_));              \
    }                                                                          \
    _Pragma("unroll")                                                          \
    for (int kk = 0; kk < 2; ++kk)                                             \
      _Pragma("unroll")                                                        \
      for (int mi = 0; mi < 4; ++mi)                                           \
        _Pragma("unroll")                                                      \
        for (int ni = 0; ni < 4; ++ni)                                         \
          acc[mi][ni] = __builtin_amdgcn_mfma_f32_16x16x32_bf16(               \
              af[mi][kk], bfr[ni][kk], acc[mi][ni], 0, 0, 0);                  \
  }

// ---------------- GEMM1: qkv = x @ w_qkv + b, scatter to q/k/vT ----------------

__global__ __launch_bounds__(256) void gemm_qkv(const ushort* __restrict__ A,
                                                const ushort* __restrict__ Bt,
                                                const float* __restrict__ bias,
                                                ushort* __restrict__ q,
                                                ushort* __restrict__ k,
                                                ushort* __restrict__ vT) {
  __shared__ __align__(16) ushort sA[128 * 64];
  __shared__ __align__(16) ushort sB[128 * 64];
  const int tid = threadIdx.x;
  const int lane = tid & 63;
  const int w = tid >> 6;
  const int wr = w >> 1, wc = w & 1;
  const int bm = blockIdx.y * 128;
  const int bn = blockIdx.x * 128;
  const int lr = lane & 15, lg = lane >> 4;
  f32x4 acc[4][4] = {};

  for (int kt = 0; kt < 1024; kt += 64) {
    GEMM_STAGE(kt);
    __syncthreads();
    GEMM_COMPUTE();
    __syncthreads();
  }

  #pragma unroll
  for (int mi = 0; mi < 4; ++mi)
    #pragma unroll
    for (int ni = 0; ni < 4; ++ni) {
      const int col = bn + wc * 64 + ni * 16 + lr;
      const int t = col >> 10;
      const int h = (col >> 6) & 15;
      const int d = col & 63;
      const float bb = bias[col];
      #pragma unroll
      for (int r = 0; r < 4; ++r) {
        const int row = bm + wr * 64 + mi * 16 + lg * 4 + r;
        const int b_ = row >> 11, n = row & 2047;
        const int bh = b_ * 16 + h;
        const ushort hv = f2bf(acc[mi][ni][r] + bb);
        if (t == 0)      q[((size_t)bh * 2048 + n) * 64 + d] = hv;
        else if (t == 1) k[((size_t)bh * 2048 + n) * 64 + d] = hv;
        else             vT[((size_t)bh * 64 + d) * 2048 + n] = hv;
      }
    }
}

// ---------------- GEMM2: out = attn @ w_out + b_out (f32 out) ----------------

__global__ __launch_bounds__(256) void gemm_out(const ushort* __restrict__ A,
                                                const ushort* __restrict__ Bt,
                                                const float* __restrict__ bias,
                                                float* __restrict__ out) {
  __shared__ __align__(16) ushort sA[128 * 64];
  __shared__ __align__(16) ushort sB[128 * 64];
  const int tid = threadIdx.x;
  const int lane = tid & 63;
  const int w = tid >> 6;
  const int wr = w >> 1, wc = w & 1;
  const int bm = blockIdx.y * 128;
  const int bn = blockIdx.x * 128;
  const int lr = lane & 15, lg = lane >> 4;
  f32x4 acc[4][4] = {};

  for (int kt = 0; kt < 1024; kt += 64) {
    GEMM_STAGE(kt);
    __syncthreads();
    GEMM_COMPUTE();
    __syncthreads();
  }

  #pragma unroll
  for (int mi = 0; mi < 4; ++mi)
    #pragma unroll
    for (int ni = 0; ni < 4; ++ni) {
      const int col = bn + wc * 64 + ni * 16 + lr;
      const float bb = bias[col];
      #pragma unroll
      for (int r = 0; r < 4; ++r) {
        const int row = bm + wr * 64 + mi * 16 + lg * 4 + r;
        out[(size_t)row * 1024 + col] = acc[mi][ni][r] + bb;
      }
    }
}

// ---------------- flash attention v4: 32x32 MFMA, in-register P ----------------

__global__ __launch_bounds__(512, 2) void attn_fwd(const ushort* __restrict__ q,
                                                   const ushort* __restrict__ k,
                                                   const ushort* __restrict__ vT,
                                                   ushort* __restrict__ o) {
  __shared__ __align__(16) ushort sK[2][64 * 64];
  __shared__ __align__(16) ushort sV[2][64 * 64];

  const int tid = threadIdx.x, lane = tid & 63, w = tid >> 6;
  const int id = blockIdx.x;
  const int xcd = id & 7, j = id >> 3;
  const int bh = xcd * 8 + (j & 7);
  const int qx = j >> 3;
  const int qrow0 = qx * 256 + w * 32;

  const ushort* Qb = q + (size_t)bh * 2048 * 64;
  const ushort* Kb = k + (size_t)bh * 2048 * 64;
  const ushort* Vb = vT + (size_t)bh * 64 * 2048;
  const int lq = lane & 31, hi = lane >> 5;

  const int srow = lane >> 3;
  const int ssw = ((lane & 7) ^ srow) * 8;
  const int krow = w * 8 + srow;

  gload_lds16(Kb + (size_t)krow * 64 + ssw, &sK[0][w * 512]);
  gload_lds16(Vb + (size_t)krow * 2048 + 0 + ssw, &sV[0][w * 512]);

  const float qs = 0.125f * 1.44269504f;  // 1/sqrt(64) * log2(e)
  bf16x8 qf[4];
  #pragma unroll
  for (int dk = 0; dk < 4; ++dk) {
    bf16x8 t = *(const bf16x8*)(Qb + (size_t)(qrow0 + lq) * 64 + dk * 16 + hi * 8);
    #pragma unroll
    for (int jj = 0; jj < 8; ++jj)
      t[jj] = (short)f2bf(bf2f((ushort)t[jj]) * qs);
    qf[dk] = t;
  }

  float m_run = -1e30f, l_run = 0.f;
  f32x16 oacc[2] = {};

  for (int t = 0; t < 32; ++t) {
    const int cur = t & 1;
    if (t + 1 < 32) {
      const int kv2 = (t + 1) << 6;
      gload_lds16(Kb + (size_t)(kv2 + krow) * 64 + ssw, &sK[cur ^ 1][w * 512]);
      gload_lds16(Vb + (size_t)krow * 2048 + kv2 + ssw, &sV[cur ^ 1][w * 512]);
      asm volatile("s_waitcnt vmcnt(2)" ::: "memory");
    } else {
      asm volatile("s_waitcnt vmcnt(0)" ::: "memory");
    }
    __builtin_amdgcn_s_barrier();
    __builtin_amdgcn_sched_barrier(0);

    const char* kb_ = (const char*)&sK[cur][0];
    const char* vb_ = (const char*)&sV[cur][0];

    f32x16 S[2] = {};
    __builtin_amdgcn_s_setprio(1);
    #pragma unroll
    for (int kvt = 0; kvt < 2; ++kvt) {
      const int row = kvt * 32 + lq;
      const int rsw = (row & 7) << 4;
      #pragma unroll
      for (int dk = 0; dk < 4; ++dk) {
        bf16x8 kf = *(const bf16x8*)(kb_ + row * 128 + ((dk * 32 + hi * 16) ^ rsw));
        S[kvt] = __builtin_amdgcn_mfma_f32_32x32x16_bf16(kf, qf[dk], S[kvt], 0, 0, 0);
      }
    }
    __builtin_amdgcn_s_setprio(0);

    float mx = S[0][0];
    #pragma unroll
    for (int kvt = 0; kvt < 2; ++kvt)
      #pragma unroll
      for (int r = 0; r < 16; ++r) mx = fmaxf(mx, S[kvt][r]);
    const float rm = fmaxf(mx, __shfl_xor(mx, 32, 64));

    if (!__all(rm <= m_run + 8.f)) {
      const float mnew = fmaxf(m_run, rm);
      const float corr = __builtin_amdgcn_exp2f(m_run - mnew);
      m_run = mnew;
      l_run *= corr;
      float cq[16];
      #pragma unroll
      for (int r = 0; r < 16; ++r)
        cq[r] = __shfl(corr, (r & 3) + 8 * (r >> 2) + 4 * hi, 64);
      #pragma unroll
      for (int dt = 0; dt < 2; ++dt)
        #pragma unroll
        for (int r = 0; r < 16; ++r) oacc[dt][r] *= cq[r];
    }

    float psum = 0.f;
    unsigned pk_[2][8];
    #pragma unroll
    for (int kvt = 0; kvt < 2; ++kvt) {
      float e[16];
      #pragma unroll
      for (int r = 0; r < 16; ++r) {
        e[r] = __builtin_amdgcn_exp2f(S[kvt][r] - m_run);
        psum += e[r];
      }
      #pragma unroll
      for (int g = 0; g < 4; ++g) {
        pk_[kvt][g * 2 + 0] = cvt_pk_bf16(e[4 * g + 0], e[4 * g + 1]);
        pk_[kvt][g * 2 + 1] = cvt_pk_bf16(e[4 * g + 2], e[4 * g + 3]);
      }
    }
    psum += __shfl_xor(psum, 32, 64);
    l_run += psum;

    __builtin_amdgcn_s_setprio(1);
    #pragma unroll
    for (int kvt = 0; kvt < 2; ++kvt)
      #pragma unroll
      for (int cc = 0; cc < 2; ++cc) {
        unsigned x0 = pk_[kvt][4 * cc + 0], x1 = pk_[kvt][4 * cc + 1];
        unsigned y0 = pk_[kvt][4 * cc + 2], y1 = pk_[kvt][4 * cc + 3];
        permlane32_swap(x0, y0);
        permlane32_swap(x1, y1);
        union { unsigned u[4]; bf16x8 v; } Am;
        Am.u[0] = x0; Am.u[1] = x1; Am.u[2] = y0; Am.u[3] = y1;
        const int cg = kvt * 2 + cc;
        #pragma unroll
        for (int dt = 0; dt < 2; ++dt) {
          const int row = dt * 32 + lq;
          bf16x8 vf = *(const bf16x8*)(vb_ + row * 128 + ((cg * 32 + hi * 16) ^ ((row & 7) << 4)));
          oacc[dt] = __builtin_amdgcn_mfma_f32_32x32x16_bf16(Am.v, vf, oacc[dt], 0, 0, 0);
        }
      }
    __builtin_amdgcn_s_setprio(0);
    __builtin_amdgcn_s_barrier();
  }

  const int b_ = bh >> 4, h = bh & 15;
  float lf[16];
  #pragma unroll
  for (int r = 0; r < 16; ++r)
    lf[r] = __builtin_amdgcn_rcpf(__shfl(l_run, (r & 3) + 8 * (r >> 2) + 4 * hi, 64));
  #pragma unroll
  for (int dt = 0; dt < 2; ++dt)
    #pragma unroll
    for (int r = 0; r < 16; ++r) {
      const int n = qrow0 + (r & 3) + 8 * (r >> 2) + 4 * hi;
      o[(((size_t)b_ * 2048 + n) * 16 + h) * 64 + dt * 32 + lq] = f2bf(oacc[dt][r] * lf[r]);
    }
}

// ---------------- launch ----------------

extern "C" void kernel_launch(void* const* d_in, const int* in_sizes, int n_in,
                              void* d_out, int out_size, void* d_ws, size_t ws_size,
                              hipStream_t stream) {
  const float* x = (const float*)d_in[0];
  const float* w_qkv = (const float*)d_in[1];
  const float* b_qkv = (const float*)d_in[2];
  const float* w_out = (const float*)d_in[3];
  const float* b_out = (const float*)d_in[4];
  float* out = (float*)d_out;
  char* ws = (char*)d_ws;

  ushort* xb    = (ushort*)(ws);                 // 16 MiB
  ushort* wqkvT = (ushort*)(ws + 16777216);      // 6 MiB
  ushort* woutT = (ushort*)(ws + 23068672);      // 2 MiB
  ushort* qb    = (ushort*)(ws + 25165824);      // 16 MiB
  ushort* kb    = (ushort*)(ws + 41943040);      // 16 MiB
  ushort* vTb   = (ushort*)(ws + 58720256);      // 16 MiB
  ushort* attnb = (ushort*)(ws + 75497472);      // 16 MiB

  cvt_f32_bf16<<<2048, 256, 0, stream>>>(x, xb, 8192 * 1024);
  transpose_cvt<<<dim3(96, 32), dim3(32, 8), 0, stream>>>(w_qkv, wqkvT, 1024, 3072);
  transpose_cvt<<<dim3(32, 32), dim3(32, 8), 0, stream>>>(w_out, woutT, 1024, 1024);
  gemm_qkv<<<dim3(24, 64), 256, 0, stream>>>(xb, wqkvT, b_qkv, qb, kb, vTb);
  attn_fwd<<<512, 512, 0, stream>>>(qb, kb, vTb, attnb);
  gemm_out<<<dim3(8, 64), 256, 0, stream>>>(attnb, woutT, b_out, out);
}

// Round 7
// 196.481 us; speedup vs baseline: 1.1228x; 1.1095x over previous
//
#include <hip/hip_runtime.h>

typedef __attribute__((ext_vector_type(8))) short bf16x8;
typedef __attribute__((ext_vector_type(4))) float f32x4;
typedef __attribute__((ext_vector_type(16))) float f32x16;

__device__ __forceinline__ ushort f2bf(float f) {
  union { float f; unsigned u; } v; v.f = f;
  unsigned r = v.u + 0x7fffu + ((v.u >> 16) & 1u);
  return (ushort)(r >> 16);
}

__device__ __forceinline__ float bf2f(ushort u) {
  union { float f; unsigned u; } v; v.u = (unsigned)u << 16;
  return v.f;
}

__device__ __forceinline__ unsigned cvt_pk_bf16(float lo, float hi) {
  unsigned r;
  asm("v_cvt_pk_bf16_f32 %0, %1, %2" : "=v"(r) : "v"(lo), "v"(hi));
  return r;
}

__device__ __forceinline__ void permlane32_swap(unsigned& x, unsigned& y) {
  asm("v_permlane32_swap_b32 %0, %1" : "+v"(x), "+v"(y));
}

__device__ __forceinline__ void gload_lds16(const void* g, void* l) {
  __builtin_amdgcn_global_load_lds(
      (const __attribute__((address_space(1))) void*)g,
      (__attribute__((address_space(3))) void*)l, 16, 0, 0);
}

// ---------------- conversion kernels ----------------

__global__ void cvt_f32_bf16(const float* __restrict__ s, ushort* __restrict__ d, int n) {
  int i = (blockIdx.x * blockDim.x + threadIdx.x) * 4;
  int stride = gridDim.x * blockDim.x * 4;
  for (; i < n; i += stride) {
    float4 v = *reinterpret_cast<const float4*>(s + i);
    ushort4 o;
    o.x = f2bf(v.x); o.y = f2bf(v.y); o.z = f2bf(v.z); o.w = f2bf(v.w);
    *reinterpret_cast<ushort4*>(d + i) = o;
  }
}

// src [R][C] f32 -> dst [C][R] bf16
__global__ void transpose_cvt(const float* __restrict__ src, ushort* __restrict__ dst,
                              int R, int C) {
  __shared__ float tile[32][33];
  int c0 = blockIdx.x * 32, r0 = blockIdx.y * 32;
  int tx = threadIdx.x, ty = threadIdx.y;  // 32 x 8
  #pragma unroll
  for (int i = 0; i < 32; i += 8)
    tile[ty + i][tx] = src[(size_t)(r0 + ty + i) * C + c0 + tx];
  __syncthreads();
  #pragma unroll
  for (int i = 0; i < 32; i += 8)
    dst[(size_t)(c0 + ty + i) * R + r0 + tx] = f2bf(tile[tx][ty + i]);
}

// ---------------- GEMM core: 128x128 tile, BK=64, XOR-swizzled LDS ----------------
// m97 2-barrier structure. LDS rows 128 B (8 x 16B chunks); chunk slot = j ^ (row&7)
// via inverse-swizzled global source (rule #21); b128 reads conflict-free.

#define GEMM_STAGE(Ap, Bp, kt)                                                 \
  {                                                                            \
    _Pragma("unroll")                                                          \
    for (int c_ = 0; c_ < 4; ++c_) {                                           \
      const int qq_ = c_ * 256 + tid;                                          \
      const int row_ = qq_ >> 3;                                               \
      const int so_ = ((qq_ & 7) ^ (row_ & 7)) * 8;                            \
      gload_lds16(Ap + (size_t)(bm + row_) * 1024 + (kt) + so_,                \
                  (char*)sA + qq_ * 16);                                       \
      gload_lds16(Bp + (size_t)(bn + row_) * 1024 + (kt) + so_,                \
                  (char*)sB + qq_ * 16);                                       \
    }                                                                          \
  }

#define GEMM_COMPUTE()                                                         \
  {                                                                            \
    bf16x8 af[4][2], bfr[4][2];                                                \
    _Pragma("unroll")                                                          \
    for (int mi = 0; mi < 4; ++mi) {                                           \
      const int row_ = wr * 64 + mi * 16 + lr;                                 \
      const char* p_ = (const char*)sA + row_ * 128;                           \
      const int sw_ = (row_ & 7) << 4;                                         \
      af[mi][0] = *(const bf16x8*)(p_ + ((lg * 16) ^ sw_));                    \
      af[mi][1] = *(const bf16x8*)(p_ + ((64 + lg * 16) ^ sw_));               \
    }                                                                          \
    _Pragma("unroll")                                                          \
    for (int ni = 0; ni < 4; ++ni) {                                           \
      const int row_ = wc * 64 + ni * 16 + lr;                                 \
      const char* p_ = (const char*)sB + row_ * 128;                           \
      const int sw_ = (row_ & 7) << 4;                                         \
      bfr[ni][0] = *(const bf16x8*)(p_ + ((lg * 16) ^ sw_));                   \
      bfr[ni][1] = *(const bf16x8*)(p_ + ((64 + lg * 16) ^ sw_));              \
    }                                                                          \
    _Pragma("unroll")                                                          \
    for (int kk = 0; kk < 2; ++kk)                                             \
      _Pragma("unroll")                                                        \
      for (int mi = 0; mi < 4; ++mi)                                           \
        _Pragma("unroll")                                                      \
        for (int ni = 0; ni < 4; ++ni)                                         \
          acc[mi][ni] = __builtin_amdgcn_mfma_f32_16x16x32_bf16(               \
              af[mi][kk], bfr[ni][kk], acc[mi][ni], 0, 0, 0);                  \
  }

#define GEMM_PROLOG                                                            \
  __shared__ __align__(16) ushort sA[128 * 64];                                \
  __shared__ __align__(16) ushort sB[128 * 64];                                \
  const int tid = threadIdx.x;                                                 \
  const int lane = tid & 63;                                                   \
  const int w = tid >> 6;                                                      \
  const int wr = w >> 1, wc = w & 1;                                           \
  const int lr = lane & 15, lg = lane >> 4;                                    \
  f32x4 acc[4][4] = {};

// ---------------- GEMM1a: [q|k] = x @ w_qkv[:, :2048] + b ----------------

__global__ __launch_bounds__(256) void gemm_qk(const ushort* __restrict__ A,
                                               const ushort* __restrict__ Bt,
                                               const float* __restrict__ bias,
                                               ushort* __restrict__ q,
                                               ushort* __restrict__ k) {
  GEMM_PROLOG;
  const int bm = blockIdx.y * 128;
  const int bn = blockIdx.x * 128;   // 0..2047: q cols then k cols

  for (int kt = 0; kt < 1024; kt += 64) {
    GEMM_STAGE(A, Bt, kt);
    __syncthreads();
    GEMM_COMPUTE();
    __syncthreads();
  }

  ushort* const dst = (bn < 1024) ? q : k;   // block-uniform
  const int cb = bn & 1023;
  #pragma unroll
  for (int mi = 0; mi < 4; ++mi)
    #pragma unroll
    for (int ni = 0; ni < 4; ++ni) {
      const int cq = cb + wc * 64 + ni * 16 + lr;
      const int h = cq >> 6, d = cq & 63;
      const float bb = bias[bn + wc * 64 + ni * 16 + lr];
      #pragma unroll
      for (int r = 0; r < 4; ++r) {
        const int row = bm + wr * 64 + mi * 16 + lg * 4 + r;
        const int b_ = row >> 11, n = row & 2047;
        const int bh = b_ * 16 + h;
        dst[((size_t)bh * 2048 + n) * 64 + d] = f2bf(acc[mi][ni][r] + bb);
      }
    }
}

// ---------------- GEMM1b: vT = (w_qkv[:, 2048:])^T @ x^T, natural [vcol][token] ----
// A = wqkvT v-rows (M = 1024 v-cols), B = x rows (N = 8192 tokens).
// D[m=vcol][n=token] maps straight onto vT[bh][d][n]: stores lr-contiguous.

__global__ __launch_bounds__(256) void gemm_vT(const ushort* __restrict__ A,
                                               const ushort* __restrict__ Bt,
                                               const float* __restrict__ bias,
                                               ushort* __restrict__ vT) {
  GEMM_PROLOG;
  const int bm = blockIdx.y * 128;   // v-col block (0..1023)
  const int bn = blockIdx.x * 128;   // token block (0..8191)

  for (int kt = 0; kt < 1024; kt += 64) {
    GEMM_STAGE(A, Bt, kt);
    __syncthreads();
    GEMM_COMPUTE();
    __syncthreads();
  }

  const int b_ = bn >> 11, n0 = bn & 2047;
  #pragma unroll
  for (int mi = 0; mi < 4; ++mi)
    #pragma unroll
    for (int ni = 0; ni < 4; ++ni) {
      const int ncol = wc * 64 + ni * 16 + lr;
      #pragma unroll
      for (int r = 0; r < 4; ++r) {
        const int m = wr * 64 + mi * 16 + lg * 4 + r;   // v-col local
        const int vc = bm + m;
        const int h = vc >> 6, d = vc & 63;
        const int bh = b_ * 16 + h;
        const float bb = bias[vc];
        vT[((size_t)bh * 64 + d) * 2048 + n0 + ncol] = f2bf(acc[mi][ni][r] + bb);
      }
    }
}

// ---------------- GEMM2: out = attn @ w_out + b_out (f32 out) ----------------

__global__ __launch_bounds__(256) void gemm_out(const ushort* __restrict__ A,
                                                const ushort* __restrict__ Bt,
                                                const float* __restrict__ bias,
                                                float* __restrict__ out) {
  GEMM_PROLOG;
  const int bm = blockIdx.y * 128;
  const int bn = blockIdx.x * 128;

  for (int kt = 0; kt < 1024; kt += 64) {
    GEMM_STAGE(A, Bt, kt);
    __syncthreads();
    GEMM_COMPUTE();
    __syncthreads();
  }

  #pragma unroll
  for (int mi = 0; mi < 4; ++mi)
    #pragma unroll
    for (int ni = 0; ni < 4; ++ni) {
      const int col = bn + wc * 64 + ni * 16 + lr;
      const float bb = bias[col];
      #pragma unroll
      for (int r = 0; r < 4; ++r) {
        const int row = bm + wr * 64 + mi * 16 + lg * 4 + r;
        out[(size_t)row * 1024 + col] = acc[mi][ni][r] + bb;
      }
    }
}

// ---------------- flash attention v4: 32x32 MFMA, in-register P ----------------

__global__ __launch_bounds__(512, 2) void attn_fwd(const ushort* __restrict__ q,
                                                   const ushort* __restrict__ k,
                                                   const ushort* __restrict__ vT,
                                                   ushort* __restrict__ o) {
  __shared__ __align__(16) ushort sK[2][64 * 64];
  __shared__ __align__(16) ushort sV[2][64 * 64];

  const int tid = threadIdx.x, lane = tid & 63, w = tid >> 6;
  const int id = blockIdx.x;
  const int xcd = id & 7, j = id >> 3;
  const int bh = xcd * 8 + (j & 7);
  const int qx = j >> 3;
  const int qrow0 = qx * 256 + w * 32;

  const ushort* Qb = q + (size_t)bh * 2048 * 64;
  const ushort* Kb = k + (size_t)bh * 2048 * 64;
  const ushort* Vb = vT + (size_t)bh * 64 * 2048;
  const int lq = lane & 31, hi = lane >> 5;

  const int srow = lane >> 3;
  const int ssw = ((lane & 7) ^ srow) * 8;
  const int krow = w * 8 + srow;

  gload_lds16(Kb + (size_t)krow * 64 + ssw, &sK[0][w * 512]);
  gload_lds16(Vb + (size_t)krow * 2048 + 0 + ssw, &sV[0][w * 512]);

  const float qs = 0.125f * 1.44269504f;  // 1/sqrt(64) * log2(e)
  bf16x8 qf[4];
  #pragma unroll
  for (int dk = 0; dk < 4; ++dk) {
    bf16x8 t = *(const bf16x8*)(Qb + (size_t)(qrow0 + lq) * 64 + dk * 16 + hi * 8);
    #pragma unroll
    for (int jj = 0; jj < 8; ++jj)
      t[jj] = (short)f2bf(bf2f((ushort)t[jj]) * qs);
    qf[dk] = t;
  }

  float m_run = -1e30f, l_run = 0.f;
  f32x16 oacc[2] = {};

  for (int t = 0; t < 32; ++t) {
    const int cur = t & 1;
    if (t + 1 < 32) {
      const int kv2 = (t + 1) << 6;
      gload_lds16(Kb + (size_t)(kv2 + krow) * 64 + ssw, &sK[cur ^ 1][w * 512]);
      gload_lds16(Vb + (size_t)krow * 2048 + kv2 + ssw, &sV[cur ^ 1][w * 512]);
      asm volatile("s_waitcnt vmcnt(2)" ::: "memory");
    } else {
      asm volatile("s_waitcnt vmcnt(0)" ::: "memory");
    }
    __builtin_amdgcn_s_barrier();
    __builtin_amdgcn_sched_barrier(0);

    const char* kb_ = (const char*)&sK[cur][0];
    const char* vb_ = (const char*)&sV[cur][0];

    f32x16 S[2] = {};
    __builtin_amdgcn_s_setprio(1);
    #pragma unroll
    for (int kvt = 0; kvt < 2; ++kvt) {
      const int row = kvt * 32 + lq;
      const int rsw = (row & 7) << 4;
      #pragma unroll
      for (int dk = 0; dk < 4; ++dk) {
        bf16x8 kf = *(const bf16x8*)(kb_ + row * 128 + ((dk * 32 + hi * 16) ^ rsw));
        S[kvt] = __builtin_amdgcn_mfma_f32_32x32x16_bf16(kf, qf[dk], S[kvt], 0, 0, 0);
      }
    }
    __builtin_amdgcn_s_setprio(0);

    float mx = S[0][0];
    #pragma unroll
    for (int kvt = 0; kvt < 2; ++kvt)
      #pragma unroll
      for (int r = 0; r < 16; ++r) mx = fmaxf(mx, S[kvt][r]);
    const float rm = fmaxf(mx, __shfl_xor(mx, 32, 64));

    if (!__all(rm <= m_run + 8.f)) {
      const float mnew = fmaxf(m_run, rm);
      const float corr = __builtin_amdgcn_exp2f(m_run - mnew);
      m_run = mnew;
      l_run *= corr;
      float cq[16];
      #pragma unroll
      for (int r = 0; r < 16; ++r)
        cq[r] = __shfl(corr, (r & 3) + 8 * (r >> 2) + 4 * hi, 64);
      #pragma unroll
      for (int dt = 0; dt < 2; ++dt)
        #pragma unroll
        for (int r = 0; r < 16; ++r) oacc[dt][r] *= cq[r];
    }

    float psum = 0.f;
    unsigned pk_[2][8];
    #pragma unroll
    for (int kvt = 0; kvt < 2; ++kvt) {
      float e[16];
      #pragma unroll
      for (int r = 0; r < 16; ++r) {
        e[r] = __builtin_amdgcn_exp2f(S[kvt][r] - m_run);
        psum += e[r];
      }
      #pragma unroll
      for (int g = 0; g < 4; ++g) {
        pk_[kvt][g * 2 + 0] = cvt_pk_bf16(e[4 * g + 0], e[4 * g + 1]);
        pk_[kvt][g * 2 + 1] = cvt_pk_bf16(e[4 * g + 2], e[4 * g + 3]);
      }
    }
    psum += __shfl_xor(psum, 32, 64);
    l_run += psum;

    __builtin_amdgcn_s_setprio(1);
    #pragma unroll
    for (int kvt = 0; kvt < 2; ++kvt)
      #pragma unroll
      for (int cc = 0; cc < 2; ++cc) {
        unsigned x0 = pk_[kvt][4 * cc + 0], x1 = pk_[kvt][4 * cc + 1];
        unsigned y0 = pk_[kvt][4 * cc + 2], y1 = pk_[kvt][4 * cc + 3];
        permlane32_swap(x0, y0);
        permlane32_swap(x1, y1);
        union { unsigned u[4]; bf16x8 v; } Am;
        Am.u[0] = x0; Am.u[1] = x1; Am.u[2] = y0; Am.u[3] = y1;
        const int cg = kvt * 2 + cc;
        #pragma unroll
        for (int dt = 0; dt < 2; ++dt) {
          const int row = dt * 32 + lq;
          bf16x8 vf = *(const bf16x8*)(vb_ + row * 128 + ((cg * 32 + hi * 16) ^ ((row & 7) << 4)));
          oacc[dt] = __builtin_amdgcn_mfma_f32_32x32x16_bf16(Am.v, vf, oacc[dt], 0, 0, 0);
        }
      }
    __builtin_amdgcn_s_setprio(0);
    __builtin_amdgcn_s_barrier();
  }

  const int b_ = bh >> 4, h = bh & 15;
  float lf[16];
  #pragma unroll
  for (int r = 0; r < 16; ++r)
    lf[r] = __builtin_amdgcn_rcpf(__shfl(l_run, (r & 3) + 8 * (r >> 2) + 4 * hi, 64));
  #pragma unroll
  for (int dt = 0; dt < 2; ++dt)
    #pragma unroll
    for (int r = 0; r < 16; ++r) {
      const int n = qrow0 + (r & 3) + 8 * (r >> 2) + 4 * hi;
      o[(((size_t)b_ * 2048 + n) * 16 + h) * 64 + dt * 32 + lq] = f2bf(oacc[dt][r] * lf[r]);
    }
}

// ---------------- launch ----------------

extern "C" void kernel_launch(void* const* d_in, const int* in_sizes, int n_in,
                              void* d_out, int out_size, void* d_ws, size_t ws_size,
                              hipStream_t stream) {
  const float* x = (const float*)d_in[0];
  const float* w_qkv = (const float*)d_in[1];
  const float* b_qkv = (const float*)d_in[2];
  const float* w_out = (const float*)d_in[3];
  const float* b_out = (const float*)d_in[4];
  float* out = (float*)d_out;
  char* ws = (char*)d_ws;

  ushort* xb    = (ushort*)(ws);                 // 16 MiB
  ushort* wqkvT = (ushort*)(ws + 16777216);      // 6 MiB
  ushort* woutT = (ushort*)(ws + 23068672);      // 2 MiB
  ushort* qb    = (ushort*)(ws + 25165824);      // 16 MiB
  ushort* kb    = (ushort*)(ws + 41943040);      // 16 MiB
  ushort* vTb   = (ushort*)(ws + 58720256);      // 16 MiB
  ushort* attnb = (ushort*)(ws + 75497472);      // 16 MiB

  cvt_f32_bf16<<<2048, 256, 0, stream>>>(x, xb, 8192 * 1024);
  transpose_cvt<<<dim3(96, 32), dim3(32, 8), 0, stream>>>(w_qkv, wqkvT, 1024, 3072);
  transpose_cvt<<<dim3(32, 32), dim3(32, 8), 0, stream>>>(w_out, woutT, 1024, 1024);
  gemm_qk<<<dim3(16, 64), 256, 0, stream>>>(xb, wqkvT, b_qkv, qb, kb);
  gemm_vT<<<dim3(64, 8), 256, 0, stream>>>(wqkvT + 2048 * 1024, xb, b_qkv + 2048, vTb);
  attn_fwd<<<512, 512, 0, stream>>>(qb, kb, vTb, attnb);
  gemm_out<<<dim3(8, 64), 256, 0, stream>>>(attnb, woutT, b_out, out);
}

// Round 8
// 195.829 us; speedup vs baseline: 1.1265x; 1.0033x over previous
//
#include <hip/hip_runtime.h>

typedef __attribute__((ext_vector_type(8))) short bf16x8;
typedef __attribute__((ext_vector_type(4))) float f32x4;
typedef __attribute__((ext_vector_type(16))) float f32x16;

__device__ __forceinline__ ushort f2bf(float f) {
  union { float f; unsigned u; } v; v.f = f;
  unsigned r = v.u + 0x7fffu + ((v.u >> 16) & 1u);
  return (ushort)(r >> 16);
}

__device__ __forceinline__ float bf2f(ushort u) {
  union { float f; unsigned u; } v; v.u = (unsigned)u << 16;
  return v.f;
}

__device__ __forceinline__ unsigned cvt_pk_bf16(float lo, float hi) {
  unsigned r;
  asm("v_cvt_pk_bf16_f32 %0, %1, %2" : "=v"(r) : "v"(lo), "v"(hi));
  return r;
}

__device__ __forceinline__ void permlane32_swap(unsigned& x, unsigned& y) {
  asm("v_permlane32_swap_b32 %0, %1" : "+v"(x), "+v"(y));
}

__device__ __forceinline__ void gload_lds16(const void* g, void* l) {
  __builtin_amdgcn_global_load_lds(
      (const __attribute__((address_space(1))) void*)g,
      (__attribute__((address_space(3))) void*)l, 16, 0, 0);
}

// ---------------- conversion kernels ----------------

__global__ void cvt_f32_bf16(const float* __restrict__ s, ushort* __restrict__ d, int n) {
  int i = (blockIdx.x * blockDim.x + threadIdx.x) * 4;
  int stride = gridDim.x * blockDim.x * 4;
  for (; i < n; i += stride) {
    float4 v = *reinterpret_cast<const float4*>(s + i);
    ushort4 o;
    o.x = f2bf(v.x); o.y = f2bf(v.y); o.z = f2bf(v.z); o.w = f2bf(v.w);
    *reinterpret_cast<ushort4*>(d + i) = o;
  }
}

// src [R][C] f32 -> dst [C][R] bf16
__global__ void transpose_cvt(const float* __restrict__ src, ushort* __restrict__ dst,
                              int R, int C) {
  __shared__ float tile[32][33];
  int c0 = blockIdx.x * 32, r0 = blockIdx.y * 32;
  int tx = threadIdx.x, ty = threadIdx.y;  // 32 x 8
  #pragma unroll
  for (int i = 0; i < 32; i += 8)
    tile[ty + i][tx] = src[(size_t)(r0 + ty + i) * C + c0 + tx];
  __syncthreads();
  #pragma unroll
  for (int i = 0; i < 32; i += 8)
    dst[(size_t)(c0 + ty + i) * R + r0 + tx] = f2bf(tile[tx][ty + i]);
}

// ---------------- GEMM core: 128x128, BK=64, double-buffered (T3 2-phase) ------
// Per K-tile: issue STAGE(T+1) -> compute tile T (ds_read + MFMA) -> vmcnt(0)
// -> s_barrier. Load latency hides under compute. LDS rows 128 B, chunk slot
// = j ^ (row&7) via inverse-swizzled global source (rule #21), conflict-free.

#define GEMM_STAGE(buf, Ap, Bp, kt)                                            \
  {                                                                            \
    _Pragma("unroll")                                                          \
    for (int c_ = 0; c_ < 4; ++c_) {                                           \
      const int qq_ = c_ * 256 + tid;                                          \
      const int row_ = qq_ >> 3;                                               \
      const int so_ = ((qq_ & 7) ^ (row_ & 7)) * 8;                            \
      gload_lds16(Ap + (size_t)(bm + row_) * 1024 + (kt) + so_,                \
                  (char*)sA + (buf) * 16384 + qq_ * 16);                       \
      gload_lds16(Bp + (size_t)(bn + row_) * 1024 + (kt) + so_,                \
                  (char*)sB + (buf) * 16384 + qq_ * 16);                       \
    }                                                                          \
  }

#define GEMM_COMPUTE(buf)                                                      \
  {                                                                            \
    const char* bA_ = (const char*)sA + (buf) * 16384;                         \
    const char* bB_ = (const char*)sB + (buf) * 16384;                         \
    bf16x8 af[4][2], bfr[4][2];                                                \
    _Pragma("unroll")                                                          \
    for (int mi = 0; mi < 4; ++mi) {                                           \
      const int row_ = wr * 64 + mi * 16 + lr;                                 \
      const char* p_ = bA_ + row_ * 128;                                       \
      const int sw_ = (row_ & 7) << 4;                                         \
      af[mi][0] = *(const bf16x8*)(p_ + ((lg * 16) ^ sw_));                    \
      af[mi][1] = *(const bf16x8*)(p_ + ((64 + lg * 16) ^ sw_));               \
    }                                                                          \
    _Pragma("unroll")                                                          \
    for (int ni = 0; ni < 4; ++ni) {                                           \
      const int row_ = wc * 64 + ni * 16 + lr;                                 \
      const char* p_ = bB_ + row_ * 128;                                       \
      const int sw_ = (row_ & 7) << 4;                                         \
      bfr[ni][0] = *(const bf16x8*)(p_ + ((lg * 16) ^ sw_));                   \
      bfr[ni][1] = *(const bf16x8*)(p_ + ((64 + lg * 16) ^ sw_));              \
    }                                                                          \
    _Pragma("unroll")                                                          \
    for (int kk = 0; kk < 2; ++kk)                                             \
      _Pragma("unroll")                                                        \
      for (int mi = 0; mi < 4; ++mi)                                           \
        _Pragma("unroll")                                                      \
        for (int ni = 0; ni < 4; ++ni)                                         \
          acc[mi][ni] = __builtin_amdgcn_mfma_f32_16x16x32_bf16(               \
              af[mi][kk], bfr[ni][kk], acc[mi][ni], 0, 0, 0);                  \
  }

#define GEMM_PIPELINE(Ap, Bp)                                                  \
  GEMM_STAGE(0, Ap, Bp, 0);                                                    \
  asm volatile("s_waitcnt vmcnt(0)" ::: "memory");                             \
  __builtin_amdgcn_s_barrier();                                                \
  __builtin_amdgcn_sched_barrier(0);                                           \
  for (int T = 0; T < 16; ++T) {                                               \
    if (T + 1 < 16) GEMM_STAGE((T + 1) & 1, Ap, Bp, (T + 1) * 64);             \
    GEMM_COMPUTE(T & 1);                                                       \
    asm volatile("s_waitcnt vmcnt(0)" ::: "memory");                           \
    __builtin_amdgcn_s_barrier();                                              \
    __builtin_amdgcn_sched_barrier(0);                                         \
  }

#define GEMM_PROLOG                                                            \
  __shared__ __align__(16) ushort sA[2][128 * 64];                             \
  __shared__ __align__(16) ushort sB[2][128 * 64];                             \
  const int tid = threadIdx.x;                                                 \
  const int lane = tid & 63;                                                   \
  const int w = tid >> 6;                                                      \
  const int wr = w >> 1, wc = w & 1;                                           \
  const int lr = lane & 15, lg = lane >> 4;                                    \
  f32x4 acc[4][4] = {};

// ---------------- GEMM1a: [q|k] = x @ w_qkv[:, :2048] + b ----------------
// 1024 blocks; XCD-swizzled: XCD c owns A-row-panels by in [c*8, c*8+8).

__global__ __launch_bounds__(256) void gemm_qk(const ushort* __restrict__ A,
                                               const ushort* __restrict__ Bt,
                                               const float* __restrict__ bias,
                                               ushort* __restrict__ q,
                                               ushort* __restrict__ k) {
  GEMM_PROLOG;
  const int id = blockIdx.x;
  const int xcd = id & 7, j = id >> 3;      // j in [0,128)
  const int by = xcd * 8 + (j & 7);         // [0,64)
  const int bx = j >> 3;                    // [0,16)
  const int bm = by * 128;
  const int bn = bx * 128;

  GEMM_PIPELINE(A, Bt);

  ushort* const dst = (bn < 1024) ? q : k;   // block-uniform
  const int cb = bn & 1023;
  #pragma unroll
  for (int mi = 0; mi < 4; ++mi)
    #pragma unroll
    for (int ni = 0; ni < 4; ++ni) {
      const int cq = cb + wc * 64 + ni * 16 + lr;
      const int h = cq >> 6, d = cq & 63;
      const float bb = bias[bn + wc * 64 + ni * 16 + lr];
      #pragma unroll
      for (int r = 0; r < 4; ++r) {
        const int row = bm + wr * 64 + mi * 16 + lg * 4 + r;
        const int b_ = row >> 11, n = row & 2047;
        const int bh = b_ * 16 + h;
        dst[((size_t)bh * 2048 + n) * 64 + d] = f2bf(acc[mi][ni][r] + bb);
      }
    }
}

// ---------------- GEMM1b: vT = (w_qkv v-cols)^T @ x^T, natural [vcol][token] ----

__global__ __launch_bounds__(256) void gemm_vT(const ushort* __restrict__ A,
                                               const ushort* __restrict__ Bt,
                                               const float* __restrict__ bias,
                                               ushort* __restrict__ vT) {
  GEMM_PROLOG;
  const int id = blockIdx.x;                // 512 blocks
  const int xcd = id & 7, j = id >> 3;      // j in [0,64)
  const int bnb = xcd * 8 + (j & 7);        // token-block [0,64)
  const int bmb = j >> 3;                   // v-col block [0,8)
  const int bm = bmb * 128;
  const int bn = bnb * 128;

  GEMM_PIPELINE(A, Bt);

  const int b_ = bn >> 11, n0 = bn & 2047;
  #pragma unroll
  for (int mi = 0; mi < 4; ++mi)
    #pragma unroll
    for (int ni = 0; ni < 4; ++ni) {
      const int ncol = wc * 64 + ni * 16 + lr;
      #pragma unroll
      for (int r = 0; r < 4; ++r) {
        const int m = wr * 64 + mi * 16 + lg * 4 + r;
        const int vc = bm + m;
        const int h = vc >> 6, d = vc & 63;
        const int bh = b_ * 16 + h;
        const float bb = bias[vc];
        vT[((size_t)bh * 64 + d) * 2048 + n0 + ncol] = f2bf(acc[mi][ni][r] + bb);
      }
    }
}

// ---------------- GEMM2: out = attn @ w_out + b_out (f32 out) ----------------

__global__ __launch_bounds__(256) void gemm_out(const ushort* __restrict__ A,
                                                const ushort* __restrict__ Bt,
                                                const float* __restrict__ bias,
                                                float* __restrict__ out) {
  GEMM_PROLOG;
  const int id = blockIdx.x;                // 512 blocks
  const int xcd = id & 7, j = id >> 3;      // j in [0,64)
  const int by = xcd * 8 + (j & 7);         // A-row block [0,64)
  const int bx = j >> 3;                    // col block [0,8)
  const int bm = by * 128;
  const int bn = bx * 128;

  GEMM_PIPELINE(A, Bt);

  #pragma unroll
  for (int mi = 0; mi < 4; ++mi)
    #pragma unroll
    for (int ni = 0; ni < 4; ++ni) {
      const int col = bn + wc * 64 + ni * 16 + lr;
      const float bb = bias[col];
      #pragma unroll
      for (int r = 0; r < 4; ++r) {
        const int row = bm + wr * 64 + mi * 16 + lg * 4 + r;
        out[(size_t)row * 1024 + col] = acc[mi][ni][r] + bb;
      }
    }
}

// ---------------- flash attention v4: 32x32 MFMA, in-register P ----------------

__global__ __launch_bounds__(512, 2) void attn_fwd(const ushort* __restrict__ q,
                                                   const ushort* __restrict__ k,
                                                   const ushort* __restrict__ vT,
                                                   ushort* __restrict__ o) {
  __shared__ __align__(16) ushort sK[2][64 * 64];
  __shared__ __align__(16) ushort sV[2][64 * 64];

  const int tid = threadIdx.x, lane = tid & 63, w = tid >> 6;
  const int id = blockIdx.x;
  const int xcd = id & 7, j = id >> 3;
  const int bh = xcd * 8 + (j & 7);
  const int qx = j >> 3;
  const int qrow0 = qx * 256 + w * 32;

  const ushort* Qb = q + (size_t)bh * 2048 * 64;
  const ushort* Kb = k + (size_t)bh * 2048 * 64;
  const ushort* Vb = vT + (size_t)bh * 64 * 2048;
  const int lq = lane & 31, hi = lane >> 5;

  const int srow = lane >> 3;
  const int ssw = ((lane & 7) ^ srow) * 8;
  const int krow = w * 8 + srow;

  gload_lds16(Kb + (size_t)krow * 64 + ssw, &sK[0][w * 512]);
  gload_lds16(Vb + (size_t)krow * 2048 + 0 + ssw, &sV[0][w * 512]);

  const float qs = 0.125f * 1.44269504f;  // 1/sqrt(64) * log2(e)
  bf16x8 qf[4];
  #pragma unroll
  for (int dk = 0; dk < 4; ++dk) {
    bf16x8 t = *(const bf16x8*)(Qb + (size_t)(qrow0 + lq) * 64 + dk * 16 + hi * 8);
    #pragma unroll
    for (int jj = 0; jj < 8; ++jj)
      t[jj] = (short)f2bf(bf2f((ushort)t[jj]) * qs);
    qf[dk] = t;
  }

  float m_run = -1e30f, l_run = 0.f;
  f32x16 oacc[2] = {};

  for (int t = 0; t < 32; ++t) {
    const int cur = t & 1;
    if (t + 1 < 32) {
      const int kv2 = (t + 1) << 6;
      gload_lds16(Kb + (size_t)(kv2 + krow) * 64 + ssw, &sK[cur ^ 1][w * 512]);
      gload_lds16(Vb + (size_t)krow * 2048 + kv2 + ssw, &sV[cur ^ 1][w * 512]);
      asm volatile("s_waitcnt vmcnt(2)" ::: "memory");
    } else {
      asm volatile("s_waitcnt vmcnt(0)" ::: "memory");
    }
    __builtin_amdgcn_s_barrier();
    __builtin_amdgcn_sched_barrier(0);

    const char* kb_ = (const char*)&sK[cur][0];
    const char* vb_ = (const char*)&sV[cur][0];

    f32x16 S[2] = {};
    __builtin_amdgcn_s_setprio(1);
    #pragma unroll
    for (int kvt = 0; kvt < 2; ++kvt) {
      const int row = kvt * 32 + lq;
      const int rsw = (row & 7) << 4;
      #pragma unroll
      for (int dk = 0; dk < 4; ++dk) {
        bf16x8 kf = *(const bf16x8*)(kb_ + row * 128 + ((dk * 32 + hi * 16) ^ rsw));
        S[kvt] = __builtin_amdgcn_mfma_f32_32x32x16_bf16(kf, qf[dk], S[kvt], 0, 0, 0);
      }
    }
    __builtin_amdgcn_s_setprio(0);

    float mx = S[0][0];
    #pragma unroll
    for (int kvt = 0; kvt < 2; ++kvt)
      #pragma unroll
      for (int r = 0; r < 16; ++r) mx = fmaxf(mx, S[kvt][r]);
    const float rm = fmaxf(mx, __shfl_xor(mx, 32, 64));

    if (!__all(rm <= m_run + 8.f)) {
      const float mnew = fmaxf(m_run, rm);
      const float corr = __builtin_amdgcn_exp2f(m_run - mnew);
      m_run = mnew;
      l_run *= corr;
      float cq[16];
      #pragma unroll
      for (int r = 0; r < 16; ++r)
        cq[r] = __shfl(corr, (r & 3) + 8 * (r >> 2) + 4 * hi, 64);
      #pragma unroll
      for (int dt = 0; dt < 2; ++dt)
        #pragma unroll
        for (int r = 0; r < 16; ++r) oacc[dt][r] *= cq[r];
    }

    float psum = 0.f;
    unsigned pk_[2][8];
    #pragma unroll
    for (int kvt = 0; kvt < 2; ++kvt) {
      float e[16];
      #pragma unroll
      for (int r = 0; r < 16; ++r) {
        e[r] = __builtin_amdgcn_exp2f(S[kvt][r] - m_run);
        psum += e[r];
      }
      #pragma unroll
      for (int g = 0; g < 4; ++g) {
        pk_[kvt][g * 2 + 0] = cvt_pk_bf16(e[4 * g + 0], e[4 * g + 1]);
        pk_[kvt][g * 2 + 1] = cvt_pk_bf16(e[4 * g + 2], e[4 * g + 3]);
      }
    }
    psum += __shfl_xor(psum, 32, 64);
    l_run += psum;

    __builtin_amdgcn_s_setprio(1);
    #pragma unroll
    for (int kvt = 0; kvt < 2; ++kvt)
      #pragma unroll
      for (int cc = 0; cc < 2; ++cc) {
        unsigned x0 = pk_[kvt][4 * cc + 0], x1 = pk_[kvt][4 * cc + 1];
        unsigned y0 = pk_[kvt][4 * cc + 2], y1 = pk_[kvt][4 * cc + 3];
        permlane32_swap(x0, y0);
        permlane32_swap(x1, y1);
        union { unsigned u[4]; bf16x8 v; } Am;
        Am.u[0] = x0; Am.u[1] = x1; Am.u[2] = y0; Am.u[3] = y1;
        const int cg = kvt * 2 + cc;
        #pragma unroll
        for (int dt = 0; dt < 2; ++dt) {
          const int row = dt * 32 + lq;
          bf16x8 vf = *(const bf16x8*)(vb_ + row * 128 + ((cg * 32 + hi * 16) ^ ((row & 7) << 4)));
          oacc[dt] = __builtin_amdgcn_mfma_f32_32x32x16_bf16(Am.v, vf, oacc[dt], 0, 0, 0);
        }
      }
    __builtin_amdgcn_s_setprio(0);
    __builtin_amdgcn_s_barrier();
  }

  const int b_ = bh >> 4, h = bh & 15;
  float lf[16];
  #pragma unroll
  for (int r = 0; r < 16; ++r)
    lf[r] = __builtin_amdgcn_rcpf(__shfl(l_run, (r & 3) + 8 * (r >> 2) + 4 * hi, 64));
  #pragma unroll
  for (int dt = 0; dt < 2; ++dt)
    #pragma unroll
    for (int r = 0; r < 16; ++r) {
      const int n = qrow0 + (r & 3) + 8 * (r >> 2) + 4 * hi;
      o[(((size_t)b_ * 2048 + n) * 16 + h) * 64 + dt * 32 + lq] = f2bf(oacc[dt][r] * lf[r]);
    }
}

// ---------------- launch ----------------

extern "C" void kernel_launch(void* const* d_in, const int* in_sizes, int n_in,
                              void* d_out, int out_size, void* d_ws, size_t ws_size,
                              hipStream_t stream) {
  const float* x = (const float*)d_in[0];
  const float* w_qkv = (const float*)d_in[1];
  const float* b_qkv = (const float*)d_in[2];
  const float* w_out = (const float*)d_in[3];
  const float* b_out = (const float*)d_in[4];
  float* out = (float*)d_out;
  char* ws = (char*)d_ws;

  ushort* xb    = (ushort*)(ws);                 // 16 MiB
  ushort* wqkvT = (ushort*)(ws + 16777216);      // 6 MiB
  ushort* woutT = (ushort*)(ws + 23068672);      // 2 MiB
  ushort* qb    = (ushort*)(ws + 25165824);      // 16 MiB
  ushort* kb    = (ushort*)(ws + 41943040);      // 16 MiB
  ushort* vTb   = (ushort*)(ws + 58720256);      // 16 MiB
  ushort* attnb = (ushort*)(ws + 75497472);      // 16 MiB

  cvt_f32_bf16<<<2048, 256, 0, stream>>>(x, xb, 8192 * 1024);
  transpose_cvt<<<dim3(96, 32), dim3(32, 8), 0, stream>>>(w_qkv, wqkvT, 1024, 3072);
  transpose_cvt<<<dim3(32, 32), dim3(32, 8), 0, stream>>>(w_out, woutT, 1024, 1024);
  gemm_qk<<<1024, 256, 0, stream>>>(xb, wqkvT, b_qkv, qb, kb);
  gemm_vT<<<512, 256, 0, stream>>>(wqkvT + 2048 * 1024, xb, b_qkv + 2048, vTb);
  attn_fwd<<<512, 512, 0, stream>>>(qb, kb, vTb, attnb);
  gemm_out<<<512, 256, 0, stream>>>(attnb, woutT, b_out, out);
}